// Round 1
// baseline (67.363 us; speedup 1.0000x reference)
//
#include <hip/hip_runtime.h>

#define EPS 1e-3f
#define Bn 16
#define Tn 2048
#define Dn 256
#define Kn 8
#define TS 32            // t-chunks per batch row
#define TCH (Tn / TS)    // 64 t per block

__device__ __forceinline__ float fexp2(float x) {
#if __has_builtin(__builtin_amdgcn_exp2f)
    return __builtin_amdgcn_exp2f(x);
#else
    return exp2f(x);
#endif
}

__device__ __forceinline__ float frcp(float x) {
#if __has_builtin(__builtin_amdgcn_rcpf)
    return __builtin_amdgcn_rcpf(x);
#else
    return 1.0f / x;
#endif
}

// Pass 1: accumulate S[k,d] = sum_{b,t} tau ; A1[k,b,d] = sum_t tau*x ;
//         A3[k,b,d] = sum_t tau^3 * x^2
__global__ __launch_bounds__(256) void ucb_pass1(
    const float* __restrict__ X, const float* __restrict__ Mean,
    const float* __restrict__ Var,
    float* __restrict__ S, float* __restrict__ A1, float* __restrict__ A3)
{
    const int d  = threadIdx.x;          // 0..255 (= Dn)
    const int tc = blockIdx.x;           // t-chunk
    const int b  = blockIdx.y;           // batch

    const float L2E = 1.4426950408889634f;
    float Ak[Kn], Bk[Kn], Gk[Kn];
#pragma unroll
    for (int k = 0; k < Kn; ++k) {
        float m  = Mean[k * Dn + d];
        float v  = Var[k * Dn + d];
        float sp = logf(1.0f + expf(v));          // softplus
        float c2 = -0.5f * L2E / (sp + EPS);      // exp -> exp2 with folded log2e
        Ak[k] = c2;
        Bk[k] = -2.0f * c2 * m;
        Gk[k] = c2 * m * m;
    }

    float s0[Kn], s1[Kn], s3[Kn];
#pragma unroll
    for (int k = 0; k < Kn; ++k) { s0[k] = 0.f; s1[k] = 0.f; s3[k] = 0.f; }

    const float* xp = X + ((size_t)b * Tn + (size_t)tc * TCH) * Dn + d;
#pragma unroll 4
    for (int t = 0; t < TCH; ++t) {
        float x = xp[(size_t)t * Dn];
        float p[Kn];
        float sum = EPS;
#pragma unroll
        for (int k = 0; k < Kn; ++k) {
            float arg = fmaf(fmaf(Ak[k], x, Bk[k]), x, Gk[k]);
            p[k] = fexp2(arg);
            sum += p[k];
        }
        float inv = frcp(sum);
        float xx  = x * x;
#pragma unroll
        for (int k = 0; k < Kn; ++k) {
            float tau = p[k] * inv;
            s0[k] += tau;
            s1[k]  = fmaf(tau, x, s1[k]);
            float t3 = tau * tau * tau;
            s3[k]  = fmaf(t3, xx, s3[k]);
        }
    }

#pragma unroll
    for (int k = 0; k < Kn; ++k) {
        atomicAdd(&S [k * Dn + d],                      s0[k]);
        atomicAdd(&A1[((size_t)k * Bn + b) * Dn + d],   s1[k]);
        atomicAdd(&A3[((size_t)k * Bn + b) * Dn + d],   s3[k]);
    }
}

// Pass 2: out[b,t,d] = inv_sum_p * sum_k p_k * (Rk*x - REk)
__global__ __launch_bounds__(256) void ucb_pass2(
    const float* __restrict__ X, const float* __restrict__ Mean,
    const float* __restrict__ Var,
    const float* __restrict__ S, const float* __restrict__ A1,
    const float* __restrict__ A3, float* __restrict__ Out)
{
    const int d  = threadIdx.x;
    const int tc = blockIdx.x;
    const int b  = blockIdx.y;

    const float L2E = 1.4426950408889634f;
    const float rs  = rsqrtf(1.0f + EPS);   // 1/sqrt(pri+eps), pri==1

    float Ak[Kn], Bk[Kn], Gk[Kn], Rk[Kn], REk[Kn];
#pragma unroll
    for (int k = 0; k < Kn; ++k) {
        float m  = Mean[k * Dn + d];
        float v  = Var[k * Dn + d];
        float sp = logf(1.0f + expf(v));
        float c2 = -0.5f * L2E / (sp + EPS);
        Ak[k] = c2;
        Bk[k] = -2.0f * c2 * m;
        Gk[k] = c2 * m * m;

        float s  = S[k * Dn + d];
        float iS = 1.0f / (s + EPS);
        float a1 = A1[((size_t)k * Bn + b) * Dn + d];
        float a3 = A3[((size_t)k * Bn + b) * Dn + d];
        float E  = a1 * iS * (1.0f / Tn);
        float V  = a3 * iS * iS * iS * (1.0f / Tn);
        float r  = rs * rsqrtf(V + EPS);
        Rk[k]  = r;
        REk[k] = r * E;
    }

    const size_t base = ((size_t)b * Tn + (size_t)tc * TCH) * Dn + d;
#pragma unroll 4
    for (int t = 0; t < TCH; ++t) {
        float x = X[base + (size_t)t * Dn];
        float p[Kn];
        float sum = EPS;
#pragma unroll
        for (int k = 0; k < Kn; ++k) {
            float arg = fmaf(fmaf(Ak[k], x, Bk[k]), x, Gk[k]);
            p[k] = fexp2(arg);
            sum += p[k];
        }
        float inv = frcp(sum);
        float acc = 0.f;
#pragma unroll
        for (int k = 0; k < Kn; ++k) {
            acc = fmaf(p[k], fmaf(Rk[k], x, -REk[k]), acc);
        }
        Out[base + (size_t)t * Dn] = acc * inv;
    }
}

extern "C" void kernel_launch(void* const* d_in, const int* in_sizes, int n_in,
                              void* d_out, int out_size, void* d_ws, size_t ws_size,
                              hipStream_t stream)
{
    const float* x    = (const float*)d_in[0];
    const float* mean = (const float*)d_in[1];
    const float* var  = (const float*)d_in[2];
    // d_in[3] = prior: softmax over a singleton axis == 1.0, only enters as
    // 1/sqrt(1+eps) -> compile-time constant; unused.

    float* S  = (float*)d_ws;                       // K*D
    float* A1 = S  + (size_t)Kn * Dn;               // K*B*D
    float* A3 = A1 + (size_t)Kn * Bn * Dn;          // K*B*D

    size_t zero_bytes = ((size_t)Kn * Dn + 2 * (size_t)Kn * Bn * Dn) * sizeof(float);
    hipMemsetAsync(d_ws, 0, zero_bytes, stream);

    dim3 grid(TS, Bn), block(256);
    ucb_pass1<<<grid, block, 0, stream>>>(x, mean, var, S, A1, A3);
    ucb_pass2<<<grid, block, 0, stream>>>(x, mean, var, S, A1, A3, (float*)d_out);
}